// Round 10
// baseline (195.555 us; speedup 1.0000x reference)
//
#include <hip/hip_runtime.h>
#include <math.h>

#define B_ 32
#define NODES_ 512
#define IN_ 256
#define OUT_ 128
#define CAPS_ 16
#define KW_ 5
#define M_ (B_*NODES_)            // 16384
#define N_ (KW_*OUT_)             // 640
#define NCH 32                    // node chunks of 16

typedef __attribute__((ext_vector_type(8))) short short8;
typedef __attribute__((ext_vector_type(4))) float f32x4;

// ---- workspace layout (bytes) ---- (round-5 proven: 51,642,368 total)
#define Y_BOFF   0
#define L_BOFF   41943040
#define V_BOFF   42991616
#define SP_BOFF  43253760
#define BT_SZ    (N_*IN_*2)       // 327,680 bytes each

__device__ __forceinline__ float b2f(unsigned short u) {
  union { unsigned int i; float f; } c; c.i = ((unsigned int)u) << 16; return c.f;
}
// f32 -> bf16 round-to-nearest-even (finite inputs only)
__device__ __forceinline__ unsigned short f2b(float f) {
  union { float f; unsigned int i; } c; c.f = f;
  unsigned int u = c.i;
  u += 0x7fffu + ((u >> 16) & 1u);
  return (unsigned short)(u >> 16);
}
__device__ __forceinline__ void async_load16(const void* g, void* l) {
  __builtin_amdgcn_global_load_lds(
      (const __attribute__((address_space(1))) unsigned int*)g,
      (__attribute__((address_space(3))) unsigned int*)l, 16, 0, 0);
}

// ============================================================
// conv_w: split W into K-MAJOR bf16 hi/lo panels:
//   bT*[kg][n][j] = W[k][i=kg*8+j][o],  n = k*128+o, kg = i/8.
// ============================================================
__global__ __launch_bounds__(256) void conv_w(const float* __restrict__ W,
                                              unsigned short* __restrict__ bThi,
                                              unsigned short* __restrict__ bTlo) {
  int n = blockIdx.x;           // 0..639
  int i = threadIdx.x;          // 0..255
  int k = n >> 7, o = n & 127;
  float v = W[((size_t)k*IN_ + i)*OUT_ + o];
  unsigned short h = f2b(v);
  size_t dst = ((size_t)(i >> 3)*N_ + n)*8 + (i & 7);
  bThi[dst] = h;
  bTlo[dst] = f2b(v - b2f(h));
}

// ============================================================
// gemm_fn: y[m][n] = sum_i x[m][i]*bT[n][i]  (split-bf16 MFMA
// hi*hi + hi*lo + lo*hi, f32 accumulate). FULL-N blocks: 256
// blocks x 64 rows x all 640 cols -> x read exactly once.
// A: reg-staged COALESCED (was 512 scattered 16B async reads/step);
// B: flat contiguous gload_lds (k-major panels).
// ============================================================
__global__ __launch_bounds__(512) void gemm_fn(const float* __restrict__ x,
                                               const unsigned short* __restrict__ bThi,
                                               const unsigned short* __restrict__ bTlo,
                                               float* __restrict__ y) {
  __shared__ float A_lds[8*64*4];      //  8 KB [cg][row][4f]
  __shared__ short Bh_lds[4*640*8];    // 40 KB [kg][n][8]
  __shared__ short Bl_lds[4*640*8];    // 40 KB
  const int t    = threadIdx.x;
  const int w    = t >> 6;             // wave 0..7 -> N-strip w*80
  const int lane = t & 63;
  const int lrow = lane & 15;
  const int lk   = lane >> 4;          // 0..3
  const int m0   = blockIdx.x * 64;
  const int wn0  = w * 80;
  const int arow = t >> 3;             // 0..63 (A stage)
  const int ac4  = t & 7;              // 0..7

  f32x4 acc[4][5];
  #pragma unroll
  for (int i=0;i<4;++i)
    #pragma unroll
    for (int j=0;j<5;++j) acc[i][j] = (f32x4){0.f,0.f,0.f,0.f};

  for (int kbi = 0; kbi < 8; ++kbi) {
    const int kb = kbi*32;
    // ---- stage B hi/lo: flat contiguous 40 KB each ----
    const unsigned short* bh_src = bThi + (size_t)kbi*4*N_*8;
    const unsigned short* bl_src = bTlo + (size_t)kbi*4*N_*8;
    #pragma unroll
    for (int q=0; q<5; ++q) {
      int db = q*512 + w*64;           // wave-uniform chunk base
      async_load16(bh_src + (size_t)(db + lane)*8, &Bh_lds[db*8]);
      async_load16(bl_src + (size_t)(db + lane)*8, &Bl_lds[db*8]);
    }
    // ---- stage A coalesced via regs: thread = (row, 4-col group) ----
    {
      float4 av = *(const float4*)(x + (size_t)(m0 + arow)*IN_ + kb + ac4*4);
      *(float4*)&A_lds[((ac4*64) + arow)*4] = av;
    }
    __syncthreads();

    // ---- A fragments: read f32, split hi/lo in-register ----
    short8 ah[4], al[4];
    #pragma unroll
    for (int mi=0; mi<4; ++mi) {
      int row = mi*16 + lrow;
      f32x4 a0 = *(const f32x4*)&A_lds[((2*lk  )*64 + row)*4];
      f32x4 a1 = *(const f32x4*)&A_lds[((2*lk+1)*64 + row)*4];
      #pragma unroll
      for (int j=0; j<8; ++j) {
        float f = (j < 4) ? a0[j] : a1[j-4];
        unsigned short h = f2b(f);
        ah[mi][j] = (short)h;
        al[mi][j] = (short)f2b(f - b2f(h));
      }
    }
    // ---- MFMA: 5 n-frags x 4 m-frags x 3 passes ----
    #pragma unroll
    for (int ni=0; ni<5; ++ni) {
      int nb = wn0 + ni*16 + lrow;
      short8 bh = *(const short8*)&Bh_lds[(lk*N_ + nb)*8];
      short8 bl = *(const short8*)&Bl_lds[(lk*N_ + nb)*8];
      #pragma unroll
      for (int mi=0; mi<4; ++mi) {
        acc[mi][ni] = __builtin_amdgcn_mfma_f32_16x16x32_bf16(bh, ah[mi], acc[mi][ni], 0, 0, 0);
        acc[mi][ni] = __builtin_amdgcn_mfma_f32_16x16x32_bf16(bh, al[mi], acc[mi][ni], 0, 0, 0);
        acc[mi][ni] = __builtin_amdgcn_mfma_f32_16x16x32_bf16(bl, ah[mi], acc[mi][ni], 0, 0, 0);
      }
    }
    __syncthreads();
  }

  // epilogue: lane holds C[m = lane&15][n-quad = (lane>>4)*4 + reg]
  #pragma unroll
  for (int mi=0; mi<4; ++mi) {
    int m = m0 + mi*16 + lrow;
    #pragma unroll
    for (int ni=0; ni<5; ++ni) {
      int nb = wn0 + ni*16 + lk*4;
      float4 o = {acc[mi][ni][0], acc[mi][ni][1], acc[mi][ni][2], acc[mi][ni][3]};
      *(float4*)(y + (size_t)m*N_ + nb) = o;
    }
  }
}

// ============================================================
// route4: one routing sweep; each block (512 thr, 1/CU) loops over
// FOUR 16-node chunks with async-STAGE split: next chunk's y/alpha/
// logits loaded into registers BEFORE compute of current chunk ->
// HBM/L3 latency hides under phase-1/2; per-block fixed costs /4.
// Math identical to proven rounds 5/6 (pad-644 y, f32 everywhere).
// ============================================================
__global__ __launch_bounds__(512) void route4(const float* __restrict__ y,
                                              const float* __restrict__ alpha,
                                              const float* __restrict__ contrib,
                                              float* __restrict__ logits,
                                              const float* __restrict__ vin,
                                              float* __restrict__ s_part,
                                              int mode) {
  __shared__ __align__(16) float sh_y[16*644];      // 41.2 KB [node][k*128+o]
  __shared__ __align__(16) float sh_v[16*132];      //  8.4 KB [cap][o]
  __shared__ __align__(16) float sh_alpha[16*16*5]; //  5.1 KB [node][cap][k]
  __shared__ float sh_logit[16][16];
  __shared__ float sh_cw[16][16];

  const int t = threadIdx.x;
  const int g = blockIdx.x;    // 0..7 : chunk group (4 chunks)
  const int b = blockIdx.y;    // 0..31

  // ---- stage v once per sweep (mode>=1): 512 float4 ----
  if (mode >= 1) {
    int flat = t*4;
    float4 vv = *(const float4*)(vin + (size_t)b*CAPS_*OUT_ + flat);
    *(float4*)&sh_v[(flat >> 7)*132 + (flat & 127)] = vv;
  }

  // ---- preload chunk 0 into registers ----
  float4 yreg[5]; float4 areg = {0,0,0,0}; float lreg = 0.f;
  {
    int ch0 = g*4;
    const float* yb0 = y + (size_t)(b*NODES_ + ch0*16)*N_;
    #pragma unroll
    for (int q=0;q<5;++q) yreg[q] = *(const float4*)(yb0 + (size_t)(t + q*512)*4);
    if (t < 320) areg = *(const float4*)(alpha + (size_t)ch0*16*CAPS_*KW_ + (size_t)t*4);
    if (t < 256) {
      int node = t & 15, cap = t >> 4;
      lreg = (mode >= 1) ? logits[((size_t)b*CAPS_ + cap)*NODES_ + ch0*16 + node]
                         : contrib[(size_t)b*NODES_ + ch0*16 + node];
    }
  }

  #pragma unroll
  for (int i = 0; i < 4; ++i) {
    const int ch = g*4 + i;
    const int n0 = ch*16;

    // ---- commit staged regs to LDS ----
    #pragma unroll
    for (int q=0;q<5;++q) {
      int flat = (t + q*512)*4;
      int node = flat / 640;
      int rem  = flat - node*640;
      *(float4*)&sh_y[node*644 + rem] = yreg[q];
    }
    if (t < 320) *(float4*)&sh_alpha[t*4] = areg;
    if (t < 256) {
      int node = t & 15, cap = t >> 4;
      sh_logit[node][cap] = lreg;
      if (mode == 0) logits[((size_t)b*CAPS_ + cap)*NODES_ + n0 + node] = lreg;
    }
    __syncthreads();

    // ---- issue NEXT chunk's global loads (hide under compute) ----
    if (i < 3) {
      int ch2 = ch + 1;
      const float* ybn = y + (size_t)(b*NODES_ + ch2*16)*N_;
      #pragma unroll
      for (int q=0;q<5;++q) yreg[q] = *(const float4*)(ybn + (size_t)(t + q*512)*4);
      if (t < 320) areg = *(const float4*)(alpha + (size_t)ch2*16*CAPS_*KW_ + (size_t)t*4);
      if (t < 256) {
        int node = t & 15, cap = t >> 4;
        lreg = (mode >= 1) ? logits[((size_t)b*CAPS_ + cap)*NODES_ + ch2*16 + node]
                           : contrib[(size_t)b*NODES_ + ch2*16 + node];
      }
    }

    // ---- phase 1: a[node][cap] = sum_o u*v (2 o-halves, shfl pair) ----
    if (mode >= 1) {
      int nd = t >> 5, cap = (t >> 1) & 15, half = t & 1;
      const float* al = &sh_alpha[(nd*16+cap)*5];
      float a0=al[0],a1=al[1],a2=al[2],a3=al[3],a4=al[4];
      const float* yb = &sh_y[nd*644] + half*64;
      const float* vb = &sh_v[cap*132] + half*64;
      float accd = 0.f;
      #pragma unroll 4
      for (int o=0; o<64; o+=4) {
        float4 y0 = *(const float4*)(yb + 0*128 + o);
        float4 y1 = *(const float4*)(yb + 1*128 + o);
        float4 y2 = *(const float4*)(yb + 2*128 + o);
        float4 y3 = *(const float4*)(yb + 3*128 + o);
        float4 y4 = *(const float4*)(yb + 4*128 + o);
        float4 vv = *(const float4*)(vb + o);
        float ux = a0*y0.x + a1*y1.x + a2*y2.x + a3*y3.x + a4*y4.x;
        float uy = a0*y0.y + a1*y1.y + a2*y2.y + a3*y3.y + a4*y4.y;
        float uz = a0*y0.z + a1*y1.z + a2*y2.z + a3*y3.z + a4*y4.z;
        float uw = a0*y0.w + a1*y1.w + a2*y2.w + a3*y3.w + a4*y4.w;
        accd += ux*vv.x + uy*vv.y + uz*vv.z + uw*vv.w;
      }
      float tot = accd + __shfl_xor(accd, 1, 64);
      if (half == 0) {
        float newl = sh_logit[nd][cap] + tot;
        sh_logit[nd][cap] = newl;
        logits[((size_t)b*CAPS_ + cap)*NODES_ + n0 + nd] = newl;
      }
      __syncthreads();
      if (t < 16) {
        int nd2 = t;
        float m = -1e30f;
        #pragma unroll
        for (int c=0;c<16;++c) m = fmaxf(m, sh_logit[nd2][c]);
        float s = 0.f;
        float e[16];
        #pragma unroll
        for (int c=0;c<16;++c) { e[c] = __expf(sh_logit[nd2][c]-m); s += e[c]; }
        float inv = 1.f/s;
        #pragma unroll
        for (int c=0;c<16;++c) sh_cw[nd2][c] = e[c]*inv;
      }
    } else {
      if (t < 256) sh_cw[t & 15][t >> 4] = 1.f/16.f;
    }
    __syncthreads();

    // ---- phase 2: s_part[c][o..o+3] = sum_nd cw*u (c fast: broadcast) ----
    {
      int c = t & 15;
      int o = (t >> 4) * 4;     // 0..124
      float4 acc = {0.f,0.f,0.f,0.f};
      #pragma unroll 4
      for (int nd=0; nd<16; ++nd) {
        const float* al = &sh_alpha[(nd*16+c)*5];
        float a0=al[0],a1=al[1],a2=al[2],a3=al[3],a4=al[4];
        const float* yb = &sh_y[nd*644 + o];
        float4 y0 = *(const float4*)(yb);
        float4 y1 = *(const float4*)(yb + 128);
        float4 y2 = *(const float4*)(yb + 256);
        float4 y3 = *(const float4*)(yb + 384);
        float4 y4 = *(const float4*)(yb + 512);
        float cw = sh_cw[nd][c];
        acc.x += cw*(a0*y0.x + a1*y1.x + a2*y2.x + a3*y3.x + a4*y4.x);
        acc.y += cw*(a0*y0.y + a1*y1.y + a2*y2.y + a3*y3.y + a4*y4.y);
        acc.z += cw*(a0*y0.z + a1*y1.z + a2*y2.z + a3*y3.z + a4*y4.z);
        acc.w += cw*(a0*y0.w + a1*y1.w + a2*y2.w + a3*y3.w + a4*y4.w);
      }
      *(float4*)(s_part + ((size_t)(b*NCH + ch)*CAPS_ + c)*OUT_ + o) = acc;
    }
    __syncthreads();   // protect sh_* overwrite next iteration
  }
}

// ============================================================
// squash_k: reduce s_part over chunks, squash, write v (or out)
// ============================================================
__global__ __launch_bounds__(128) void squash_k(const float* __restrict__ s_part,
                                                float* __restrict__ out) {
  const int bc = blockIdx.x;       // b*16+c
  const int o  = threadIdx.x;      // 0..127
  const int b = bc >> 4, c = bc & 15;
  const float* sp = s_part + ((size_t)(b*NCH)*CAPS_ + c)*OUT_ + o;
  float s = 0.f;
  #pragma unroll
  for (int ch=0; ch<NCH; ++ch) s += sp[(size_t)ch*CAPS_*OUT_];
  float ss = s*s;
  #pragma unroll
  for (int off=32; off>0; off>>=1) ss += __shfl_down(ss, off, 64);
  __shared__ float red[2];
  if ((o & 63) == 0) red[o>>6] = ss;
  __syncthreads();
  float sn = red[0] + red[1];
  float scale = (sn/(1.f+sn)) / (sqrtf(sn)+1e-8f);
  out[(size_t)bc*OUT_ + o] = scale*s;
}

// ============================================================
extern "C" void kernel_launch(void* const* d_in, const int* in_sizes, int n_in,
                              void* d_out, int out_size, void* d_ws, size_t ws_size,
                              hipStream_t stream) {
  const float* x       = (const float*)d_in[0];
  const float* contrib = (const float*)d_in[1];
  const float* W       = (const float*)d_in[2];
  const float* alpha   = (const float*)d_in[3];
  float* out = (float*)d_out;
  char*  wsb = (char*)d_ws;

  float* y             = (float*)(wsb + Y_BOFF);
  float* logits        = (float*)(wsb + L_BOFF);
  float* v             = (float*)(wsb + V_BOFF);
  float* s_part        = (float*)(wsb + SP_BOFF);
  // bT hi/lo alias the s_part region (consumed before s_part first written)
  unsigned short* bThi = (unsigned short*)(wsb + SP_BOFF);
  unsigned short* bTlo = (unsigned short*)(wsb + SP_BOFF + BT_SZ);

  conv_w<<<N_, 256, 0, stream>>>(W, bThi, bTlo);
  gemm_fn<<<M_/64, 512, 0, stream>>>(x, bThi, bTlo, y);

  route4<<<dim3(8, B_), 512, 0, stream>>>(y, alpha, contrib, logits, v, s_part, 0);
  squash_k<<<B_*CAPS_, 128, 0, stream>>>(s_part, v);

  for (int it=0; it<3; ++it) {
    route4<<<dim3(8, B_), 512, 0, stream>>>(y, alpha, contrib, logits, v, s_part, 1);
    squash_k<<<B_*CAPS_, 128, 0, stream>>>(s_part, (it==2) ? out : v);
  }
}

// Round 11
// 151.446 us; speedup vs baseline: 1.2913x; 1.2913x over previous
//
#include <hip/hip_runtime.h>
#include <math.h>

#define B_ 32
#define NODES_ 512
#define IN_ 256
#define OUT_ 128
#define CAPS_ 16
#define KW_ 5
#define M_ (B_*NODES_)            // 16384
#define N_ (KW_*OUT_)             // 640
#define NCH 32                    // node chunks of 16

typedef __attribute__((ext_vector_type(8))) short short8;
typedef __attribute__((ext_vector_type(4))) float f32x4;

// ---- workspace layout (bytes) ---- (round-5 proven: 51,642,368 total)
#define Y_BOFF   0
#define L_BOFF   41943040
#define V_BOFF   42991616
#define SP_BOFF  43253760
#define BT_SZ    (N_*IN_*2)       // 327,680 bytes each

#define YPAD 648                  // 648%32==8 -> node-groups on disjoint bank octets
#define APAD 84                   // 84%32==20 -> spread alpha rows

__device__ __forceinline__ float b2f(unsigned short u) {
  union { unsigned int i; float f; } c; c.i = ((unsigned int)u) << 16; return c.f;
}
// f32 -> bf16 round-to-nearest-even (finite inputs only)
__device__ __forceinline__ unsigned short f2b(float f) {
  union { float f; unsigned int i; } c; c.f = f;
  unsigned int u = c.i;
  u += 0x7fffu + ((u >> 16) & 1u);
  return (unsigned short)(u >> 16);
}
__device__ __forceinline__ void async_load16(const void* g, void* l) {
  __builtin_amdgcn_global_load_lds(
      (const __attribute__((address_space(1))) unsigned int*)g,
      (__attribute__((address_space(3))) unsigned int*)l, 16, 0, 0);
}

// ============================================================
// conv_w: split W into K-MAJOR bf16 hi/lo panels:
//   bT*[kg][n][j] = W[k][i=kg*8+j][o],  n = k*128+o, kg = i/8.
// ============================================================
__global__ __launch_bounds__(256) void conv_w(const float* __restrict__ W,
                                              unsigned short* __restrict__ bThi,
                                              unsigned short* __restrict__ bTlo) {
  int n = blockIdx.x;           // 0..639
  int i = threadIdx.x;          // 0..255
  int k = n >> 7, o = n & 127;
  float v = W[((size_t)k*IN_ + i)*OUT_ + o];
  unsigned short h = f2b(v);
  size_t dst = ((size_t)(i >> 3)*N_ + n)*8 + (i & 7);
  bThi[dst] = h;
  bTlo[dst] = f2b(v - b2f(h));
}

// ============================================================
// gemm_fn (R10-proven, ~10-12us): FULL-N blocks, coalesced reg-staged
// A, flat gload_lds B panels, split-bf16 3-pass MFMA.
// ============================================================
__global__ __launch_bounds__(512) void gemm_fn(const float* __restrict__ x,
                                               const unsigned short* __restrict__ bThi,
                                               const unsigned short* __restrict__ bTlo,
                                               float* __restrict__ y) {
  __shared__ float A_lds[8*64*4];      //  8 KB [cg][row][4f]
  __shared__ short Bh_lds[4*640*8];    // 40 KB [kg][n][8]
  __shared__ short Bl_lds[4*640*8];    // 40 KB
  const int t    = threadIdx.x;
  const int w    = t >> 6;             // wave 0..7 -> N-strip w*80
  const int lane = t & 63;
  const int lrow = lane & 15;
  const int lk   = lane >> 4;          // 0..3
  const int m0   = blockIdx.x * 64;
  const int wn0  = w * 80;
  const int arow = t >> 3;             // 0..63 (A stage)
  const int ac4  = t & 7;              // 0..7

  f32x4 acc[4][5];
  #pragma unroll
  for (int i=0;i<4;++i)
    #pragma unroll
    for (int j=0;j<5;++j) acc[i][j] = (f32x4){0.f,0.f,0.f,0.f};

  for (int kbi = 0; kbi < 8; ++kbi) {
    const int kb = kbi*32;
    const unsigned short* bh_src = bThi + (size_t)kbi*4*N_*8;
    const unsigned short* bl_src = bTlo + (size_t)kbi*4*N_*8;
    #pragma unroll
    for (int q=0; q<5; ++q) {
      int db = q*512 + w*64;           // wave-uniform chunk base
      async_load16(bh_src + (size_t)(db + lane)*8, &Bh_lds[db*8]);
      async_load16(bl_src + (size_t)(db + lane)*8, &Bl_lds[db*8]);
    }
    {
      float4 av = *(const float4*)(x + (size_t)(m0 + arow)*IN_ + kb + ac4*4);
      *(float4*)&A_lds[((ac4*64) + arow)*4] = av;
    }
    __syncthreads();

    short8 ah[4], al[4];
    #pragma unroll
    for (int mi=0; mi<4; ++mi) {
      int row = mi*16 + lrow;
      f32x4 a0 = *(const f32x4*)&A_lds[((2*lk  )*64 + row)*4];
      f32x4 a1 = *(const f32x4*)&A_lds[((2*lk+1)*64 + row)*4];
      #pragma unroll
      for (int j=0; j<8; ++j) {
        float f = (j < 4) ? a0[j] : a1[j-4];
        unsigned short h = f2b(f);
        ah[mi][j] = (short)h;
        al[mi][j] = (short)f2b(f - b2f(h));
      }
    }
    #pragma unroll
    for (int ni=0; ni<5; ++ni) {
      int nb = wn0 + ni*16 + lrow;
      short8 bh = *(const short8*)&Bh_lds[(lk*N_ + nb)*8];
      short8 bl = *(const short8*)&Bl_lds[(lk*N_ + nb)*8];
      #pragma unroll
      for (int mi=0; mi<4; ++mi) {
        acc[mi][ni] = __builtin_amdgcn_mfma_f32_16x16x32_bf16(bh, ah[mi], acc[mi][ni], 0, 0, 0);
        acc[mi][ni] = __builtin_amdgcn_mfma_f32_16x16x32_bf16(bh, al[mi], acc[mi][ni], 0, 0, 0);
        acc[mi][ni] = __builtin_amdgcn_mfma_f32_16x16x32_bf16(bl, ah[mi], acc[mi][ni], 0, 0, 0);
      }
    }
    __syncthreads();
  }

  #pragma unroll
  for (int mi=0; mi<4; ++mi) {
    int m = m0 + mi*16 + lrow;
    #pragma unroll
    for (int ni=0; ni<5; ++ni) {
      int nb = wn0 + ni*16 + lk*4;
      float4 o = {acc[mi][ni][0], acc[mi][ni][1], acc[mi][ni][2], acc[mi][ni][3]};
      *(float4*)(y + (size_t)m*N_ + nb) = o;
    }
  }
}

// ============================================================
// route_step: one routing sweep, 16-node chunk per block (256 thr).
// Phase 1 REWRITTEN: thread = (node, o-subset s); y read once per
// (n,k,o); u for all 16 caps from 80 hoisted alpha regs; 16-lane
// shfl_xor butterfly reduces the 16 cap-dots. LDS bytes /3.
// Phase 2: R8-proven c-fast broadcast form. cw stored in sh_logit.
// ============================================================
__global__ __launch_bounds__(256) void route_step(const float* __restrict__ y,
                                                  const float* __restrict__ alpha,
                                                  const float* __restrict__ contrib,
                                                  float* __restrict__ logits,
                                                  const float* __restrict__ vin,
                                                  float* __restrict__ s_part,
                                                  int mode) {
  __shared__ __align__(16) float sh_y[16*YPAD];     // 41.5 KB [node][k*128+o]
  __shared__ __align__(16) float sh_v[16*132];      //  8.4 KB [cap][o]
  __shared__ __align__(16) float sh_alpha[16*APAD]; //  5.4 KB [node][cap*5+k]
  __shared__ float sh_logit[16][16];                // logits, then cw

  const int t  = threadIdx.x;
  const int ch = blockIdx.x;   // 0..31
  const int b  = blockIdx.y;   // 0..31
  const int n0 = ch*16;

  // ---- stage y: 16 nodes x 640 f32, reg round-trip (padded dest) ----
  const float* ybase = y + ((size_t)(b*NODES_ + n0))*N_;
  float4 yst[10];
  #pragma unroll
  for (int q=0; q<10; ++q) yst[q] = *(const float4*)(ybase + (size_t)(t + q*256)*4);
  #pragma unroll
  for (int q=0; q<10; ++q) {
    int flat = (t + q*256)*4;
    int nd   = flat / 640;
    int rem  = flat - nd*640;
    *(float4*)&sh_y[nd*YPAD + rem] = yst[q];
  }
  // ---- stage alpha (padded rows) ----
  const float* abase = alpha + (size_t)n0*CAPS_*KW_;
  for (int i = t; i < 320; i += 256) {
    float4 av = *(const float4*)(abase + i*4);
    int flat = i*4;
    int nd   = flat / 80;
    int rem  = flat - nd*80;
    *(float4*)&sh_alpha[nd*APAD + rem] = av;
  }
  if (mode >= 1) {
    const float* vbase = vin + (size_t)b*CAPS_*OUT_;
    #pragma unroll
    for (int q=0; q<2; ++q) {
      int flat = (t + q*256)*4;
      int c = flat >> 7, o = flat & 127;
      float4 vv = *(const float4*)(vbase + flat);
      *(float4*)&sh_v[c*132 + o] = vv;
    }
    int nd = t & 15, cap = t >> 4;
    sh_logit[nd][cap] = logits[((size_t)b*CAPS_ + cap)*NODES_ + n0 + nd];
  } else {
    int nd = t >> 4, cap = t & 15;
    logits[((size_t)b*CAPS_ + cap)*NODES_ + n0 + nd] = contrib[(size_t)b*NODES_ + n0 + nd];
  }
  __syncthreads();

  if (mode >= 1) {
    // ---- phase 1: thread (node = t>>4, s = t&15), o-set {s+16j} ----
    const int node = t >> 4, s = t & 15;
    float ar[16][5];
    #pragma unroll
    for (int c=0;c<16;++c)
      #pragma unroll
      for (int k=0;k<5;++k) ar[c][k] = sh_alpha[node*APAD + c*5 + k];
    float acc16[16];
    #pragma unroll
    for (int c=0;c<16;++c) acc16[c] = 0.f;
    const float* yb = &sh_y[node*YPAD];
    #pragma unroll
    for (int j=0;j<8;++j) {
      int o = s + 16*j;
      float y0=yb[o], y1=yb[128+o], y2=yb[256+o], y3=yb[384+o], y4=yb[512+o];
      #pragma unroll
      for (int c=0;c<16;++c) {
        float u = ar[c][0]*y0 + ar[c][1]*y1 + ar[c][2]*y2 + ar[c][3]*y3 + ar[c][4]*y4;
        acc16[c] += u * sh_v[c*132 + o];
      }
    }
    // 16-lane butterfly all-reduce per cap
    #pragma unroll
    for (int c=0;c<16;++c) {
      acc16[c] += __shfl_xor(acc16[c], 1, 64);
      acc16[c] += __shfl_xor(acc16[c], 2, 64);
      acc16[c] += __shfl_xor(acc16[c], 4, 64);
      acc16[c] += __shfl_xor(acc16[c], 8, 64);
    }
    // lane s owns cap=s (static-index pick, no scratch)
    float mine = 0.f;
    #pragma unroll
    for (int c=0;c<16;++c) mine = (s == c) ? acc16[c] : mine;
    float newl = sh_logit[node][s] + mine;
    sh_logit[node][s] = newl;
    logits[((size_t)b*CAPS_ + s)*NODES_ + n0 + node] = newl;
    __syncthreads();
    // softmax over caps, one thread per node; overwrite row with cw
    if (t < 16) {
      int nd = t;
      float m = -1e30f;
      #pragma unroll
      for (int c=0;c<16;++c) m = fmaxf(m, sh_logit[nd][c]);
      float ssum = 0.f;
      float e[16];
      #pragma unroll
      for (int c=0;c<16;++c) { e[c] = __expf(sh_logit[nd][c]-m); ssum += e[c]; }
      float inv = 1.f/ssum;
      #pragma unroll
      for (int c=0;c<16;++c) sh_logit[nd][c] = e[c]*inv;
    }
  } else {
    int nd = t >> 4, cap = t & 15;
    sh_logit[nd][cap] = 1.f/16.f;
  }
  __syncthreads();

  // ---- phase 2: s_part[c][o] = sum_nd cw*u (c fast -> y broadcast) ----
  float* spb = s_part + ((size_t)(b*NCH + ch))*CAPS_*OUT_;
  #pragma unroll
  for (int sl=0; sl<2; ++sl) {
    int slot = t + sl*256;
    int c  = slot & 15;
    int o  = (slot >> 4) * 4;   // 0..124
    float4 acc = {0.f,0.f,0.f,0.f};
    #pragma unroll 4
    for (int nd=0; nd<16; ++nd) {
      const float* al = &sh_alpha[nd*APAD + c*5];
      float a0=al[0],a1=al[1],a2=al[2],a3=al[3],a4=al[4];
      const float* yb = &sh_y[nd*YPAD + o];
      float4 y0 = *(const float4*)(yb);
      float4 y1 = *(const float4*)(yb + 128);
      float4 y2 = *(const float4*)(yb + 256);
      float4 y3 = *(const float4*)(yb + 384);
      float4 y4 = *(const float4*)(yb + 512);
      float cw = sh_logit[nd][c];
      acc.x += cw*(a0*y0.x + a1*y1.x + a2*y2.x + a3*y3.x + a4*y4.x);
      acc.y += cw*(a0*y0.y + a1*y1.y + a2*y2.y + a3*y3.y + a4*y4.y);
      acc.z += cw*(a0*y0.z + a1*y1.z + a2*y2.z + a3*y3.z + a4*y4.z);
      acc.w += cw*(a0*y0.w + a1*y1.w + a2*y2.w + a3*y3.w + a4*y4.w);
    }
    *(float4*)(spb + c*OUT_ + o) = acc;
  }
}

// ============================================================
// squash_k: reduce s_part over chunks, squash, write v (or out)
// ============================================================
__global__ __launch_bounds__(128) void squash_k(const float* __restrict__ s_part,
                                                float* __restrict__ out) {
  const int bc = blockIdx.x;       // b*16+c
  const int o  = threadIdx.x;      // 0..127
  const int b = bc >> 4, c = bc & 15;
  const float* sp = s_part + ((size_t)(b*NCH)*CAPS_ + c)*OUT_ + o;
  float s = 0.f;
  #pragma unroll
  for (int ch=0; ch<NCH; ++ch) s += sp[(size_t)ch*CAPS_*OUT_];
  float ss = s*s;
  #pragma unroll
  for (int off=32; off>0; off>>=1) ss += __shfl_down(ss, off, 64);
  __shared__ float red[2];
  if ((o & 63) == 0) red[o>>6] = ss;
  __syncthreads();
  float sn = red[0] + red[1];
  float scale = (sn/(1.f+sn)) / (sqrtf(sn)+1e-8f);
  out[(size_t)bc*OUT_ + o] = scale*s;
}

// ============================================================
extern "C" void kernel_launch(void* const* d_in, const int* in_sizes, int n_in,
                              void* d_out, int out_size, void* d_ws, size_t ws_size,
                              hipStream_t stream) {
  const float* x       = (const float*)d_in[0];
  const float* contrib = (const float*)d_in[1];
  const float* W       = (const float*)d_in[2];
  const float* alpha   = (const float*)d_in[3];
  float* out = (float*)d_out;
  char*  wsb = (char*)d_ws;

  float* y             = (float*)(wsb + Y_BOFF);
  float* logits        = (float*)(wsb + L_BOFF);
  float* v             = (float*)(wsb + V_BOFF);
  float* s_part        = (float*)(wsb + SP_BOFF);
  // bT hi/lo alias the s_part region (consumed before s_part first written)
  unsigned short* bThi = (unsigned short*)(wsb + SP_BOFF);
  unsigned short* bTlo = (unsigned short*)(wsb + SP_BOFF + BT_SZ);

  conv_w<<<N_, 256, 0, stream>>>(W, bThi, bTlo);
  gemm_fn<<<M_/64, 512, 0, stream>>>(x, bThi, bTlo, y);

  route_step<<<dim3(NCH, B_), 256, 0, stream>>>(y, alpha, contrib, logits, v, s_part, 0);
  squash_k<<<B_*CAPS_, 128, 0, stream>>>(s_part, v);

  for (int it=0; it<3; ++it) {
    route_step<<<dim3(NCH, B_), 256, 0, stream>>>(y, alpha, contrib, logits, v, s_part, 1);
    squash_k<<<B_*CAPS_, 128, 0, stream>>>(s_part, (it==2) ? out : v);
  }
}